// Round 15
// baseline (6514.144 us; speedup 1.0000x reference)
//
#include <hip/hip_runtime.h>
#include <cfloat>
#include <cmath>

// NoisyTopKRouter eval-mode: logits = x @ W^T, top-2 + softmax over top-2.
// N=131072, D=2048, E=16. Outputs (concatenated flat in d_out as float32):
//   [0 .. 2N)   topk indices (as float values; ref dtype int64)
//   [2N .. 4N)  gating weights (softmax over the two top logits)
//
// BIT-EXACTNESS (round 7): each (row, expert) dot computed by ONE lane over
// all of D, 4 mod-4 fma chains ascending, reduced (c0+c1)+(c2+c3).
//
// R15 = R8's proven 4-wave __syncthreads skeleton + three fixes:
//  1. ALIAS-SPLIT dbuf: xs0/xs1 are distinct __shared__ arrays, loop
//     unrolled x2 (compile-time buffer choice) -> compiler proves
//     stage(xs1) and ds_read(xs0) independent -> no hidden vmcnt(0)
//     drain inside the phase (the R11-R14 ~570 us serializer).
//  2. DS halved: lane = (r = lane&15, eq = lane>>4): row r is read by 4
//     lanes (4 expert-quads), 32 ds_read_b128/wave-phase (~3.1k cy/CU
//     < HBM 5.5k cy). W from global per lane (L1-hot), since per-lane
//     eq means W cannot be an SGPR broadcast.
//  3. Mid-phase stage: compute j=0..15 (their W loads precede the stage
//     in issue order), then stage(p+1), then j=16..31 -> the in-order
//     vmcnt W-after-stage stall is bounded and TLP-covered.
//
// LDS: per buffer 4 waves x 8 staging blocks x 260 floats (2 rows x 128
// + 4 pad) = 33.3 KB; two buffers -> 2 blocks/CU, 8 waves/CU.
// Read addr (r,j): (r>>1)*260 + (r&1)*128 + 4j -> quad ((r>>1)+j)%8,
// rows 2k/2k+1 + eq-broadcast = 2-way per quad = free (m136).

constexpr int D = 2048;
constexpr int E = 16;
constexpr int BLOCK = 256;          // 4 waves
constexpr int RB = 64;              // rows per block (16 per wave)
constexpr int PW = 128;             // floats of D per phase
constexpr int NP = D / PW;          // 16 phases
constexpr int BLKF = 260;           // floats per 2-row staging block (+pad)
constexpr int WSLAB = 8 * BLKF;     // 2080 floats per wave per buffer

__global__ void wt_kernel(const float* __restrict__ W, float* __restrict__ wt) {
  const int d = blockIdx.x * blockDim.x + threadIdx.x;
  if (d >= D) return;
  #pragma unroll
  for (int e = 0; e < E; ++e) wt[d * E + e] = W[e * D + d];
}

__global__ __launch_bounds__(BLOCK, 2) void router_kernel(
    const float* __restrict__ x, const float* __restrict__ wt,
    float* __restrict__ out, int N) {
  __shared__ float xs0[4][WSLAB];   // buffer A (33.3 KB)
  __shared__ float xs1[4][WSLAB];   // buffer B (33.3 KB)

  const int tid  = threadIdx.x;
  const int lane = tid & 63;
  const int wid  = tid >> 6;        // 0..3
  const int r    = lane & 15;       // row within the wave's 16
  const int eq   = lane >> 4;       // expert quad: experts 4eq..4eq+3
  const int waverow = blockIdx.x * RB + wid * 16;
  const int row  = waverow + r;
  if (waverow >= N) return;

  // staging: instr k stages rows {2k, 2k+1} x 128 floats (two contiguous
  // 512 B segments -> one 1 KB instruction). lane covers row 2k+(lane>>5),
  // f4 (lane&31). Dest: wave slab + k*BLKF, lane-linear.
  const float* gsrc = x + (size_t)(waverow + (lane >> 5)) * D + (lane & 31) * 4;

  const float4* __restrict__ wt4 = reinterpret_cast<const float4*>(wt);

  float a4[4][4];                   // a4[t][i]: chain t (d mod 4), expert 4eq+i
  #pragma unroll
  for (int t = 0; t < 4; ++t)
    #pragma unroll
    for (int i = 0; i < 4; ++i) a4[t][i] = 0.f;

  auto stage = [&](float (&buf)[4][WSLAB], int p) {
    float* ld = &buf[wid][0];
    #pragma unroll
    for (int k = 0; k < 8; ++k)
      __builtin_amdgcn_global_load_lds(
          (const __attribute__((address_space(1))) void*)(gsrc + (size_t)(2 * k) * D + p * PW),
          (__attribute__((address_space(3))) void*)(ld + k * BLKF), 16, 0, 0);
  };

  auto compute_half = [&](const float (&buf)[4][WSLAB], int p, int j0) {
    const float* ls = &buf[wid][(r >> 1) * BLKF + (r & 1) * 128];
    const int wb = p * PW * 4;      // f4 index of (d = p*128, eq = 0)
    #pragma unroll
    for (int jj = 0; jj < PW / 8; ++jj) {   // 16 j-steps per half
      const int j = j0 + jj;
      const float4 xq = *reinterpret_cast<const float4*>(ls + 4 * j);
      const float4 w0 = wt4[wb + (4 * j + 0) * 4 + eq];
      const float4 w1 = wt4[wb + (4 * j + 1) * 4 + eq];
      const float4 w2 = wt4[wb + (4 * j + 2) * 4 + eq];
      const float4 w3 = wt4[wb + (4 * j + 3) * 4 + eq];
      a4[0][0] = fmaf(xq.x, w0.x, a4[0][0]);
      a4[0][1] = fmaf(xq.x, w0.y, a4[0][1]);
      a4[0][2] = fmaf(xq.x, w0.z, a4[0][2]);
      a4[0][3] = fmaf(xq.x, w0.w, a4[0][3]);
      a4[1][0] = fmaf(xq.y, w1.x, a4[1][0]);
      a4[1][1] = fmaf(xq.y, w1.y, a4[1][1]);
      a4[1][2] = fmaf(xq.y, w1.z, a4[1][2]);
      a4[1][3] = fmaf(xq.y, w1.w, a4[1][3]);
      a4[2][0] = fmaf(xq.z, w2.x, a4[2][0]);
      a4[2][1] = fmaf(xq.z, w2.y, a4[2][1]);
      a4[2][2] = fmaf(xq.z, w2.z, a4[2][2]);
      a4[2][3] = fmaf(xq.z, w2.w, a4[2][3]);
      a4[3][0] = fmaf(xq.w, w3.x, a4[3][0]);
      a4[3][1] = fmaf(xq.w, w3.y, a4[3][1]);
      a4[3][2] = fmaf(xq.w, w3.z, a4[3][2]);
      a4[3][3] = fmaf(xq.w, w3.w, a4[3][3]);
    }
  };

  stage(xs0, 0);
  __syncthreads();

  #pragma unroll 1
  for (int p = 0; p < NP; p += 2) {
    // phase p: compute from xs0, stage p+1 into xs1 mid-phase
    compute_half(xs0, p, 0);
    if (p + 1 < NP) stage(xs1, p + 1);
    compute_half(xs0, p, PW / 8);
    __syncthreads();
    // phase p+1: compute from xs1, stage p+2 into xs0 mid-phase
    if (p + 1 < NP) {
      compute_half(xs1, p + 1, 0);
      if (p + 2 < NP) stage(xs0, p + 2);
      compute_half(xs1, p + 1, PW / 8);
      __syncthreads();
    }
  }

  // ---- local top-2 over this thread's 4 experts (ascending index,
  //      strict > => lowest index wins ties; proven rounds 8-14) ----
  float m1 = -FLT_MAX, m2 = -FLT_MAX;
  int   i1 = E, i2 = E;
  #pragma unroll
  for (int i = 0; i < 4; ++i) {
    // horizontal sum in the proven order
    const float v = (a4[0][i] + a4[1][i]) + (a4[2][i] + a4[3][i]);
    const int idx = 4 * eq + i;
    const bool gt1 = v > m1;
    const bool gt2 = v > m2;
    m2 = gt1 ? m1 : (gt2 ? v : m2);
    i2 = gt1 ? i1 : (gt2 ? idx : i2);
    m1 = gt1 ? v : m1;
    i1 = gt1 ? idx : i1;
  }

  // ---- butterfly merge across the 4 eq-groups (lane bits 4,5); selection
  //      is rounding-free; tie-break = lowest index (proven rounds 1-14) ----
  #pragma unroll
  for (int mask = 16; mask < 64; mask <<= 1) {
    const float om1 = __shfl_xor(m1, mask);
    const int   oi1 = __shfl_xor(i1, mask);
    const float om2 = __shfl_xor(m2, mask);
    const int   oi2 = __shfl_xor(i2, mask);
    const bool bwin = (om1 > m1) || (om1 == m1 && oi1 < i1);
    const float b1 = bwin ? om1 : m1; const int bi1 = bwin ? oi1 : i1;
    const float l1 = bwin ? m1 : om1; const int li1 = bwin ? i1 : oi1;
    const float b2 = bwin ? om2 : m2; const int bi2 = bwin ? oi2 : i2;
    const bool lwin = (l1 > b2) || (l1 == b2 && li1 < bi2);
    m1 = b1; i1 = bi1;
    m2 = lwin ? l1 : b2; i2 = lwin ? li1 : bi2;
  }

  if (eq == 0) {                    // lanes 0..15: contiguous stores
    const float ex  = expf(m2 - m1);      // m2 <= m1 -> ex in (0,1]
    const float inv = 1.0f / (1.0f + ex);
    float2* outi = reinterpret_cast<float2*>(out);
    float2* outw = reinterpret_cast<float2*>(out + (size_t)N * 2);
    outi[row] = make_float2((float)i1, (float)i2);
    outw[row] = make_float2(inv, ex * inv);
  }
}

extern "C" void kernel_launch(void* const* d_in, const int* in_sizes, int n_in,
                              void* d_out, int out_size, void* d_ws, size_t ws_size,
                              hipStream_t stream) {
  const float* x = (const float*)d_in[0];
  const float* W = (const float*)d_in[1];
  float* out = (float*)d_out;
  float* wt  = (float*)d_ws;               // W^T staging: D*E*4 = 128 KB
  const int N = in_sizes[0] / D;           // 131072

  wt_kernel<<<D / 256, 256, 0, stream>>>(W, wt);
  router_kernel<<<N / RB, BLOCK, 0, stream>>>(x, wt, out, N);
}

// Round 16
// 602.656 us; speedup vs baseline: 10.8091x; 10.8091x over previous
//
#include <hip/hip_runtime.h>
#include <cfloat>
#include <cmath>

// NoisyTopKRouter eval-mode: logits = x @ W^T, top-2 + softmax over top-2.
// N=131072, D=2048, E=16. Outputs (concatenated flat in d_out as float32):
//   [0 .. 2N)   topk indices (as float values; ref dtype int64)
//   [2N .. 4N)  gating weights (softmax over the two top logits)
//
// BIT-EXACTNESS (round 7): each (row, expert) dot computed by ONE lane over
// all of D, 4 mod-4 fma chains ascending, reduced (c0+c1)+(c2+c3).
//
// R16 = R8's proven 357us skeleton (stage-at-top, compute, __syncthreads)
// with exactly the surgical deltas the post-mortems justify:
//  - mapping (r = lane&15, eq = lane>>4): row r broadcast to 4 eq-lanes ->
//    32 ds_read_b128 per lane-phase, HALF of R8's 64 (R8's DS pipe time
//    equaled its HBM time; this puts DS well under HBM).
//  - #pragma unroll 4 on the j-loop: R14-proven 60-VGPR body (R15's full
//    unroll spilled at the 128 cap -> 12 GB of scratch writes).
//  - alias-split double buffer (xs0/xs1 separate arrays, p+=2 unrolled):
//    compiler proves stage(xs1) || ds_read(xs0) -> no hidden intra-phase
//    vmcnt(0) drain (the R11-R14 ~570us serializer).
//  - staging, W path (wt4 + eq, L1-hot), epilogue, stores: verbatim from
//    R14/R15 (absmax 0.0).
// Known accepted costs: 2-way LDS quad sharing within row pairs (~4 cy/
// instr); first-W-use-per-phase serializes on stage retirement (in-order
// vmcnt), covered by 8 waves/CU TLP.

constexpr int D = 2048;
constexpr int E = 16;
constexpr int BLOCK = 256;          // 4 waves
constexpr int RB = 64;              // rows per block (16 per wave)
constexpr int PW = 128;             // floats of D per phase
constexpr int NP = D / PW;          // 16 phases
constexpr int BLKF = 260;           // floats per 2-row staging block (+pad)
constexpr int WSLAB = 8 * BLKF;     // 2080 floats per wave per buffer

__global__ void wt_kernel(const float* __restrict__ W, float* __restrict__ wt) {
  const int d = blockIdx.x * blockDim.x + threadIdx.x;
  if (d >= D) return;
  #pragma unroll
  for (int e = 0; e < E; ++e) wt[d * E + e] = W[e * D + d];
}

__global__ __launch_bounds__(BLOCK, 2) void router_kernel(
    const float* __restrict__ x, const float* __restrict__ wt,
    float* __restrict__ out, int N) {
  __shared__ float xs0[4][WSLAB];   // buffer A (33.3 KB)
  __shared__ float xs1[4][WSLAB];   // buffer B (33.3 KB)

  const int tid  = threadIdx.x;
  const int lane = tid & 63;
  const int wid  = tid >> 6;        // 0..3
  const int r    = lane & 15;       // row within the wave's 16
  const int eq   = lane >> 4;       // expert quad: experts 4eq..4eq+3
  const int waverow = blockIdx.x * RB + wid * 16;
  const int row  = waverow + r;
  if (waverow >= N) return;

  // staging: instr k stages rows {2k, 2k+1} x 128 floats (two contiguous
  // 512 B segments). lane covers row 2k+(lane>>5), f4 (lane&31).
  const float* gsrc = x + (size_t)(waverow + (lane >> 5)) * D + (lane & 31) * 4;

  const float4* __restrict__ wt4 = reinterpret_cast<const float4*>(wt);

  float a4[4][4];                   // a4[t][i]: chain t (d mod 4), expert 4eq+i
  #pragma unroll
  for (int t = 0; t < 4; ++t)
    #pragma unroll
    for (int i = 0; i < 4; ++i) a4[t][i] = 0.f;

  #define STAGE(BUF, P)                                                        \
    do {                                                                       \
      float* ld_ = &BUF[wid][0];                                               \
      _Pragma("unroll")                                                        \
      for (int k_ = 0; k_ < 8; ++k_)                                           \
        __builtin_amdgcn_global_load_lds(                                      \
            (const __attribute__((address_space(1))) void*)(gsrc +             \
                (size_t)(2 * k_) * D + (P) * PW),                              \
            (__attribute__((address_space(3))) void*)(ld_ + k_ * BLKF),        \
            16, 0, 0);                                                         \
    } while (0)

  #define COMPUTE(BUF, P)                                                      \
    do {                                                                       \
      const float* ls_ = &BUF[wid][(r >> 1) * BLKF + (r & 1) * 128];           \
      const int wb_ = (P) * PW * 4;                                            \
      _Pragma("unroll 4")                                                      \
      for (int j = 0; j < PW / 4; ++j) {                                       \
        const float4 xq = *reinterpret_cast<const float4*>(ls_ + 4 * j);       \
        const float4 w0 = wt4[wb_ + (4 * j + 0) * 4 + eq];                     \
        const float4 w1 = wt4[wb_ + (4 * j + 1) * 4 + eq];                     \
        const float4 w2 = wt4[wb_ + (4 * j + 2) * 4 + eq];                     \
        const float4 w3 = wt4[wb_ + (4 * j + 3) * 4 + eq];                     \
        a4[0][0] = fmaf(xq.x, w0.x, a4[0][0]);                                 \
        a4[0][1] = fmaf(xq.x, w0.y, a4[0][1]);                                 \
        a4[0][2] = fmaf(xq.x, w0.z, a4[0][2]);                                 \
        a4[0][3] = fmaf(xq.x, w0.w, a4[0][3]);                                 \
        a4[1][0] = fmaf(xq.y, w1.x, a4[1][0]);                                 \
        a4[1][1] = fmaf(xq.y, w1.y, a4[1][1]);                                 \
        a4[1][2] = fmaf(xq.y, w1.z, a4[1][2]);                                 \
        a4[1][3] = fmaf(xq.y, w1.w, a4[1][3]);                                 \
        a4[2][0] = fmaf(xq.z, w2.x, a4[2][0]);                                 \
        a4[2][1] = fmaf(xq.z, w2.y, a4[2][1]);                                 \
        a4[2][2] = fmaf(xq.z, w2.z, a4[2][2]);                                 \
        a4[2][3] = fmaf(xq.z, w2.w, a4[2][3]);                                 \
        a4[3][0] = fmaf(xq.w, w3.x, a4[3][0]);                                 \
        a4[3][1] = fmaf(xq.w, w3.y, a4[3][1]);                                 \
        a4[3][2] = fmaf(xq.w, w3.z, a4[3][2]);                                 \
        a4[3][3] = fmaf(xq.w, w3.w, a4[3][3]);                                 \
      }                                                                        \
    } while (0)

  STAGE(xs0, 0);
  __syncthreads();

  #pragma unroll 1
  for (int p = 0; p < NP; p += 2) {
    // phase p: compute from xs0; stage p+1 into xs1 (flies under compute)
    if (p + 1 < NP) STAGE(xs1, p + 1);
    COMPUTE(xs0, p);
    __syncthreads();
    // phase p+1: compute from xs1; stage p+2 into xs0
    if (p + 1 < NP) {
      if (p + 2 < NP) STAGE(xs0, p + 2);
      COMPUTE(xs1, p + 1);
      __syncthreads();
    }
  }
  #undef STAGE
  #undef COMPUTE

  // ---- local top-2 over this thread's 4 experts (ascending index,
  //      strict > => lowest index wins ties; proven rounds 8-15) ----
  float m1 = -FLT_MAX, m2 = -FLT_MAX;
  int   i1 = E, i2 = E;
  #pragma unroll
  for (int i = 0; i < 4; ++i) {
    // horizontal sum in the proven order
    const float v = (a4[0][i] + a4[1][i]) + (a4[2][i] + a4[3][i]);
    const int idx = 4 * eq + i;
    const bool gt1 = v > m1;
    const bool gt2 = v > m2;
    m2 = gt1 ? m1 : (gt2 ? v : m2);
    i2 = gt1 ? i1 : (gt2 ? idx : i2);
    m1 = gt1 ? v : m1;
    i1 = gt1 ? idx : i1;
  }

  // ---- butterfly merge across the 4 eq-groups (lane bits 4,5); selection
  //      is rounding-free; tie-break = lowest index (proven rounds 1-15) ----
  #pragma unroll
  for (int mask = 16; mask < 64; mask <<= 1) {
    const float om1 = __shfl_xor(m1, mask);
    const int   oi1 = __shfl_xor(i1, mask);
    const float om2 = __shfl_xor(m2, mask);
    const int   oi2 = __shfl_xor(i2, mask);
    const bool bwin = (om1 > m1) || (om1 == m1 && oi1 < i1);
    const float b1 = bwin ? om1 : m1; const int bi1 = bwin ? oi1 : i1;
    const float l1 = bwin ? m1 : om1; const int li1 = bwin ? i1 : oi1;
    const float b2 = bwin ? om2 : m2; const int bi2 = bwin ? oi2 : i2;
    const bool lwin = (l1 > b2) || (l1 == b2 && li1 < bi2);
    m1 = b1; i1 = bi1;
    m2 = lwin ? l1 : b2; i2 = lwin ? li1 : bi2;
  }

  if (eq == 0) {                    // lanes 0..15: contiguous stores
    const float ex  = expf(m2 - m1);      // m2 <= m1 -> ex in (0,1]
    const float inv = 1.0f / (1.0f + ex);
    float2* outi = reinterpret_cast<float2*>(out);
    float2* outw = reinterpret_cast<float2*>(out + (size_t)N * 2);
    outi[row] = make_float2((float)i1, (float)i2);
    outw[row] = make_float2(inv, ex * inv);
  }
}

extern "C" void kernel_launch(void* const* d_in, const int* in_sizes, int n_in,
                              void* d_out, int out_size, void* d_ws, size_t ws_size,
                              hipStream_t stream) {
  const float* x = (const float*)d_in[0];
  const float* W = (const float*)d_in[1];
  float* out = (float*)d_out;
  float* wt  = (float*)d_ws;               // W^T staging: D*E*4 = 128 KB
  const int N = in_sizes[0] / D;           // 131072

  wt_kernel<<<D / 256, 256, 0, stream>>>(W, wt);
  router_kernel<<<N / RB, BLOCK, 0, stream>>>(x, wt, out, N);
}